// Round 1
// baseline (227.219 us; speedup 1.0000x reference)
//
#include <hip/hip_runtime.h>
#include <cstdint>

#define NB 8
#define NN 512
#define NC 80
#define NCL 81
#define NMS_TH 0.5f
#define SCORE_TH 0.5f
#define IMGW 1333.0f
#define IMGH 800.0f

// ---------------- Kernel 0: zero the max_conf region of d_out ----------------
__global__ __launch_bounds__(256) void k_zero(float* __restrict__ out) {
    int i = blockIdx.x * 256 + threadIdx.x;
    if (i < NB * NN) out[i] = 0.0f;
}

// ------------- Kernel 1: per-row softmax stats (max, sum of exp) -------------
// grid = NB*NN blocks, 64 threads (one wave) each. Row has NCL=81 logits.
__global__ __launch_bounds__(64) void k_softmax_stats(const float* __restrict__ logits,
                                                      float* __restrict__ stats) {
    int row = blockIdx.x;               // 0 .. NB*NN-1
    int lane = threadIdx.x;             // 0..63
    const float* p = logits + (size_t)row * NCL;
    float v0 = p[lane];                 // lane < 64 < 81 always valid
    bool has1 = (lane + 64) < NCL;      // lanes 0..16
    float v1 = has1 ? p[lane + 64] : -INFINITY;
    float m = fmaxf(v0, v1);
#pragma unroll
    for (int off = 32; off; off >>= 1) m = fmaxf(m, __shfl_xor(m, off));
    float s = expf(v0 - m) + (has1 ? expf(v1 - m) : 0.0f);
#pragma unroll
    for (int off = 32; off; off >>= 1) s += __shfl_xor(s, off);
    if (lane == 0) { stats[2 * row] = m; stats[2 * row + 1] = s; }
}

// ---------------- Kernel 2: per-(batch,class) greedy NMS ----------------
// grid = NB*NC = 640 blocks, 256 threads. Each thread owns 2 of the 512 boxes.
__global__ __launch_bounds__(256) void k_nms(const float* __restrict__ boxes,
                                             const float* __restrict__ logits,
                                             const float* __restrict__ scale,
                                             const float* __restrict__ stats,
                                             float* __restrict__ maxconf) {
    const int blk = blockIdx.x;
    const int b = blk / NC, c = blk % NC;
    const int tid = threadIdx.x;

    __shared__ uint64_t key[NN];
    __shared__ float bx1[NN], by1[NN], bx2[NN], by2[NN], bar[NN];
    __shared__ int sidx[NN];
    __shared__ unsigned char alive[NN];

    const float sx = scale[2 * b], sy = scale[2 * b + 1];

    // scores -> strict-total-order descending sort keys
    for (int n = tid; n < NN; n += 256) {
        int row = b * NN + n;
        float logit = logits[(size_t)row * NCL + (c + 1)];
        float sc = expf(logit - stats[2 * row]) / stats[2 * row + 1];
        // stable argsort(-scores): desc by score bits, ties -> lower n first
        key[n] = ((uint64_t)__float_as_uint(sc) << 32) | (uint32_t)(NN - 1 - n);
    }
    __syncthreads();

    // bitonic sort, descending
    for (int k = 2; k <= NN; k <<= 1) {
        for (int j = k >> 1; j > 0; j >>= 1) {
            for (int i = tid; i < NN; i += 256) {
                int ixj = i ^ j;
                if (ixj > i) {
                    uint64_t a = key[i], bb = key[ixj];
                    bool up = ((i & k) == 0);
                    if (up ? (a < bb) : (a > bb)) { key[i] = bb; key[ixj] = a; }
                }
            }
            __syncthreads();
        }
    }

    // gather boxes in sorted order; scale + clip; precompute area
    for (int i = tid; i < NN; i += 256) {
        uint64_t kk = key[i];
        int n = NN - 1 - (int)(kk & 0xffffffffULL);
        sidx[i] = n;
        const float* bp = boxes + ((size_t)((b * NN + n) * NC + c)) * 4;
        float x1 = fminf(fmaxf(bp[0] * sx, 0.f), IMGW);
        float y1 = fminf(fmaxf(bp[1] * sy, 0.f), IMGH);
        float x2 = fminf(fmaxf(bp[2] * sx, 0.f), IMGW);
        float y2 = fminf(fmaxf(bp[3] * sy, 0.f), IMGH);
        bx1[i] = x1; by1[i] = y1; bx2[i] = x2; by2[i] = y2;
        bar[i] = fmaxf(x2 - x1, 0.f) * fmaxf(y2 - y1, 0.f);
        alive[i] = 1;
    }
    __syncthreads();

    // greedy suppression: sequential over sorted rank i, parallel over j
    const int j0 = tid, j1 = tid + 256;
    bool a0 = true, a1 = true;
    const float X10 = 0.f; (void)X10;
    float c_x1_0 = bx1[j0], c_y1_0 = by1[j0], c_x2_0 = bx2[j0], c_y2_0 = by2[j0], c_ar_0 = bar[j0];
    float c_x1_1 = bx1[j1], c_y1_1 = by1[j1], c_x2_1 = bx2[j1], c_y2_1 = by2[j1], c_ar_1 = bar[j1];
    for (int i = 0; i < NN - 1; ++i) {
        if (alive[i]) {                 // uniform branch (LDS broadcast)
            float x1 = bx1[i], y1 = by1[i], x2 = bx2[i], y2 = by2[i], ai = bar[i];
            if (a0 && j0 > i) {
                float inter = fmaxf(fminf(x2, c_x2_0) - fmaxf(x1, c_x1_0), 0.f)
                            * fmaxf(fminf(y2, c_y2_0) - fmaxf(y1, c_y1_0), 0.f);
                if (inter / fmaxf(ai + c_ar_0 - inter, 1e-9f) > NMS_TH) { a0 = false; alive[j0] = 0; }
            }
            if (a1 && j1 > i) {
                float inter = fmaxf(fminf(x2, c_x2_1) - fmaxf(x1, c_x1_1), 0.f)
                            * fmaxf(fminf(y2, c_y2_1) - fmaxf(y1, c_y1_1), 0.f);
                if (inter / fmaxf(ai + c_ar_1 - inter, 1e-9f) > NMS_TH) { a1 = false; alive[j1] = 0; }
            }
        }
        __syncthreads();
    }

    // kept boxes contribute their score to max_conf at their ORIGINAL index
    if (a0) {
        int bits = (int)(uint32_t)(key[j0] >> 32);   // score >= 0 -> bits monotone
        atomicMax((int*)maxconf + (b * NN + sidx[j0]), bits);
    }
    if (a1) {
        int bits = (int)(uint32_t)(key[j1] >> 32);
        atomicMax((int*)maxconf + (b * NN + sidx[j1]), bits);
    }
}

// ---------------- Kernel 3: keep = (max_conf >= 0.5) ----------------
__global__ __launch_bounds__(256) void k_keep(float* __restrict__ out) {
    int i = blockIdx.x * 256 + threadIdx.x;
    if (i < NB * NN) out[NB * NN + i] = (out[i] >= SCORE_TH) ? 1.0f : 0.0f;
}

extern "C" void kernel_launch(void* const* d_in, const int* in_sizes, int n_in,
                              void* d_out, int out_size, void* d_ws, size_t ws_size,
                              hipStream_t stream) {
    const float* boxes  = (const float*)d_in[0];   // (8,512,80,4)
    const float* logits = (const float*)d_in[1];   // (8,512,81)
    const float* scale  = (const float*)d_in[2];   // (8,2)
    float* out = (float*)d_out;                    // [max_conf(4096) | keep(4096)]
    float* stats = (float*)d_ws;                   // 2 floats per (b,n) row = 32 KB

    hipLaunchKernelGGL(k_zero, dim3((NB * NN + 255) / 256), dim3(256), 0, stream, out);
    hipLaunchKernelGGL(k_softmax_stats, dim3(NB * NN), dim3(64), 0, stream, logits, stats);
    hipLaunchKernelGGL(k_nms, dim3(NB * NC), dim3(256), 0, stream,
                       boxes, logits, scale, stats, out);
    hipLaunchKernelGGL(k_keep, dim3((NB * NN + 255) / 256), dim3(256), 0, stream, out);
}

// Round 2
// 196.711 us; speedup vs baseline: 1.1551x; 1.1551x over previous
//
#include <hip/hip_runtime.h>
#include <cstdint>

#define NB 8
#define NN 512
#define NC 80
#define NCL 81
#define NMS_TH 0.5f
#define SCORE_TH 0.5f
#define IMGW 1333.0f
#define IMGH 800.0f
#define MPITCH 516   // padded row pitch (uint64 elems) for transposed mask: breaks 4KB bank stride

// ------------- Kernel 1: per-row softmax stats (max, sum) + zero max_conf ----
// grid = NB*NN blocks, 64 threads (one wave). Row has NCL=81 logits.
__global__ __launch_bounds__(64) void k_softmax_stats(const float* __restrict__ logits,
                                                      float* __restrict__ stats,
                                                      float* __restrict__ maxconf) {
    int row = blockIdx.x;
    int lane = threadIdx.x;
    const float* p = logits + (size_t)row * NCL;
    float v0 = p[lane];
    bool has1 = (lane + 64) < NCL;
    float v1 = has1 ? p[lane + 64] : -INFINITY;
    float m = fmaxf(v0, v1);
#pragma unroll
    for (int off = 32; off; off >>= 1) m = fmaxf(m, __shfl_xor(m, off));
    float s = expf(v0 - m) + (has1 ? expf(v1 - m) : 0.0f);
#pragma unroll
    for (int off = 32; off; off >>= 1) s += __shfl_xor(s, off);
    if (lane == 0) { stats[2 * row] = m; stats[2 * row + 1] = s; }
    if (lane == 1) maxconf[row] = 0.0f;   // zero the atomicMax target
}

// ---------------- Kernel 2: per-(batch,class) greedy NMS, bitmask form -------
// grid = NB*NC = 640 blocks, 256 threads (4 waves).
__global__ __launch_bounds__(256) void k_nms(const float* __restrict__ boxes,
                                             const float* __restrict__ logits,
                                             const float* __restrict__ scale,
                                             const float* __restrict__ stats,
                                             float* __restrict__ maxconf) {
    const int blk = blockIdx.x;
    const int b = blk / NC, c = blk % NC;
    const int tid = threadIdx.x;
    const int lane = tid & 63;
    const int wv = tid >> 6;

    __shared__ uint64_t key[NN];          // 4 KB  sort keys
    __shared__ float4 pbox[NN];           // 8 KB  clipped boxes, sorted order
    __shared__ float bar[NN];             // 2 KB  areas
    __shared__ int sidx[NN];              // 2 KB  sorted rank -> original n
    __shared__ uint64_t maskT[8 * MPITCH];// 33 KB suppression bits, TRANSPOSED [word][row]
    __shared__ uint64_t keepw[8];         // final keep bits

    const float sx = scale[2 * b], sy = scale[2 * b + 1];

    // ---- scores -> strict-total-order descending sort keys ----
    for (int n = tid; n < NN; n += 256) {
        int row = b * NN + n;
        float logit = logits[(size_t)row * NCL + (c + 1)];
        float sc = expf(logit - stats[2 * row]) / stats[2 * row + 1];
        key[n] = ((uint64_t)__float_as_uint(sc) << 32) | (uint32_t)(NN - 1 - n);
    }
    __syncthreads();

    // ---- bitonic sort, descending (45 barrier steps) ----
    for (int k = 2; k <= NN; k <<= 1) {
        for (int j = k >> 1; j > 0; j >>= 1) {
            for (int i = tid; i < NN; i += 256) {
                int ixj = i ^ j;
                if (ixj > i) {
                    uint64_t a = key[i], bb = key[ixj];
                    bool up = ((i & k) == 0);
                    if (up ? (a < bb) : (a > bb)) { key[i] = bb; key[ixj] = a; }
                }
            }
            __syncthreads();
        }
    }

    // ---- gather boxes in sorted order; scale + clip; area ----
    for (int i = tid; i < NN; i += 256) {
        uint64_t kk = key[i];
        int n = NN - 1 - (int)(kk & 0xffffffffULL);
        sidx[i] = n;
        float4 bp = *reinterpret_cast<const float4*>(boxes + ((size_t)((b * NN + n) * NC + c)) * 4);
        float x1 = fminf(fmaxf(bp.x * sx, 0.f), IMGW);
        float y1 = fminf(fmaxf(bp.y * sy, 0.f), IMGH);
        float x2 = fminf(fmaxf(bp.z * sx, 0.f), IMGW);
        float y2 = fminf(fmaxf(bp.w * sy, 0.f), IMGH);
        pbox[i] = make_float4(x1, y1, x2, y2);
        bar[i] = fmaxf(x2 - x1, 0.f) * fmaxf(y2 - y1, 0.f);
    }
    __syncthreads();

    // ---- suppression mask build: wave-cooperative, ballot per (row, word) ----
    // wave wv handles rows i = wv + 4k (interleaved for load balance)
    for (int k = 0; k < NN / 4; ++k) {
        const int i = wv + 4 * k;
        const float4 bi = pbox[i];      // broadcast
        const float ai = bar[i];
        const int w0 = i >> 6;
        for (int w = w0; w < 8; ++w) {
            const int j = (w << 6) | lane;
            float4 bj = pbox[j];
            float dx = fminf(bi.z, bj.z) - fmaxf(bi.x, bj.x);
            float dy = fminf(bi.w, bj.w) - fmaxf(bi.y, bj.y);
            float inter = fmaxf(dx, 0.f) * fmaxf(dy, 0.f);
            float uni = ai + bar[j] - inter;
            bool sup = (j > i) && (inter > NMS_TH * fmaxf(uni, 1e-9f));
            uint64_t m = __ballot(sup);
            if (lane == 0) maskT[w * MPITCH + i] = m;
        }
        if (lane < w0) maskT[lane * MPITCH + i] = 0;
    }
    __syncthreads();

    // ---- serial scan (wave 0): 64 groups of 8 rows, prefetched one group ahead
    if (wv == 0) {
        uint64_t rem = 0;                 // lane (lane&7) accumulates removed word (lane&7)
        uint64_t mbB[8], mdB[8];
        const int myw = lane & 7;
#pragma unroll
        for (int t = 0; t < 8; ++t) {
            mbB[t] = maskT[0 * MPITCH + t];          // rows 0..7, word 0 (broadcast)
            mdB[t] = maskT[myw * MPITCH + t];        // rows 0..7, owned word
        }
        uint64_t rw = 0, kw = 0;          // current-word removed bits / keep bits
        for (int i8 = 0; i8 < 64; ++i8) {
            const int base = i8 * 8;
            uint64_t mbC[8], mdC[8];
#pragma unroll
            for (int t = 0; t < 8; ++t) { mbC[t] = mbB[t]; mdC[t] = mdB[t]; }
            const int nbase = base + 8;
            if (nbase < NN) {
                const int nw = nbase >> 6;
#pragma unroll
                for (int t = 0; t < 8; ++t) {
                    mbB[t] = maskT[nw * MPITCH + nbase + t];
                    mdB[t] = maskT[myw * MPITCH + nbase + t];
                }
            }
            const int bitbase = (i8 & 7) * 8;
#pragma unroll
            for (int t = 0; t < 8; ++t) {
                const int bit = bitbase + t;
                if (!((rw >> bit) & 1)) {   // row base+t is alive: suppress its victims
                    rw |= mbC[t];
                    rem |= mdC[t];
                    kw |= (1ull << bit);
                }
            }
            if ((i8 & 7) == 7) {            // word boundary
                const int w = i8 >> 3;
                if (lane == 0) keepw[w] = kw;
                kw = 0;
                const int wn = w + 1;
                if (wn < 8) {               // pull accumulated word wn from its owner lane
                    uint32_t lo = __shfl((unsigned int)(rem & 0xffffffffULL), wn);
                    uint32_t hi = __shfl((unsigned int)(rem >> 32), wn);
                    rw = ((uint64_t)hi << 32) | lo;
                }
            }
        }
    }
    __syncthreads();

    // ---- output: kept boxes raise max_conf at their original index ----
    for (int r = tid; r < NN; r += 256) {
        if ((keepw[r >> 6] >> (r & 63)) & 1) {
            int bits = (int)(uint32_t)(key[r] >> 32);   // scores > 0 -> int-monotone
            atomicMax((int*)maxconf + (b * NN + sidx[r]), bits);
        }
    }
}

// ---------------- Kernel 3: keep = (max_conf >= 0.5) ----------------
__global__ __launch_bounds__(256) void k_keep(float* __restrict__ out) {
    int i = blockIdx.x * 256 + threadIdx.x;
    if (i < NB * NN) out[NB * NN + i] = (out[i] >= SCORE_TH) ? 1.0f : 0.0f;
}

extern "C" void kernel_launch(void* const* d_in, const int* in_sizes, int n_in,
                              void* d_out, int out_size, void* d_ws, size_t ws_size,
                              hipStream_t stream) {
    const float* boxes  = (const float*)d_in[0];   // (8,512,80,4)
    const float* logits = (const float*)d_in[1];   // (8,512,81)
    const float* scale  = (const float*)d_in[2];   // (8,2)
    float* out = (float*)d_out;                    // [max_conf(4096) | keep(4096)]
    float* stats = (float*)d_ws;                   // 2 floats per (b,n) row

    hipLaunchKernelGGL(k_softmax_stats, dim3(NB * NN), dim3(64), 0, stream, logits, stats, out);
    hipLaunchKernelGGL(k_nms, dim3(NB * NC), dim3(256), 0, stream,
                       boxes, logits, scale, stats, out);
    hipLaunchKernelGGL(k_keep, dim3((NB * NN + 255) / 256), dim3(256), 0, stream, out);
}

// Round 3
// 185.094 us; speedup vs baseline: 1.2276x; 1.0628x over previous
//
#include <hip/hip_runtime.h>
#include <cstdint>

#define NB 8
#define NN 512
#define NC 80
#define NCL 81
#define NMS_TH 0.5f
#define SCORE_TH 0.5f
#define IMGW 1333.0f
#define IMGH 800.0f
#define MPITCH 516   // padded row pitch (uint64 elems) for transposed mask

// ------------- Kernel 1: per-row softmax stats (max, sum) + zero max_conf ----
__global__ __launch_bounds__(64) void k_softmax_stats(const float* __restrict__ logits,
                                                      float* __restrict__ stats,
                                                      float* __restrict__ maxconf) {
    int row = blockIdx.x;
    int lane = threadIdx.x;
    const float* p = logits + (size_t)row * NCL;
    float v0 = p[lane];
    bool has1 = (lane + 64) < NCL;
    float v1 = has1 ? p[lane + 64] : -INFINITY;
    float m = fmaxf(v0, v1);
#pragma unroll
    for (int off = 32; off; off >>= 1) m = fmaxf(m, __shfl_xor(m, off));
    float s = expf(v0 - m) + (has1 ? expf(v1 - m) : 0.0f);
#pragma unroll
    for (int off = 32; off; off >>= 1) s += __shfl_xor(s, off);
    if (lane == 0) { stats[2 * row] = m; stats[2 * row + 1] = s; }
    if (lane == 1) maxconf[row] = 0.0f;
}

// ---------------- Kernel 2: per-(batch,class) greedy NMS, bitmask form -------
// grid = NB*NC = 640 blocks, 256 threads (4 waves).
__global__ __launch_bounds__(256) void k_nms(const float* __restrict__ boxes,
                                             const float* __restrict__ logits,
                                             const float* __restrict__ scale,
                                             const float* __restrict__ stats,
                                             float* __restrict__ maxconf) {
    const int blk = blockIdx.x;
    const int b = blk / NC, c = blk % NC;
    const int tid = threadIdx.x;
    const int lane = tid & 63;

    __shared__ uint64_t key[NN];          // 4 KB  sort keys
    __shared__ float4 pbox[NN];           // 8 KB  clipped boxes, sorted order
    __shared__ float bar[NN];             // 2 KB  areas
    __shared__ int sidx[NN];              // 2 KB  sorted rank -> original n
    __shared__ uint64_t maskT[8 * MPITCH];// 33 KB suppression bits, TRANSPOSED [word][row]
    __shared__ uint64_t keepw[8];

    const float sx = scale[2 * b], sy = scale[2 * b + 1];

    // ---- scores -> strict-total-order descending sort keys ----
    for (int n = tid; n < NN; n += 256) {
        int row = b * NN + n;
        float logit = logits[(size_t)row * NCL + (c + 1)];
        float sc = expf(logit - stats[2 * row]) / stats[2 * row + 1];
        key[n] = ((uint64_t)__float_as_uint(sc) << 32) | (uint32_t)(NN - 1 - n);
    }
    __syncthreads();

    // ---- bitonic sort, descending (45 barrier steps) ----
    for (int k = 2; k <= NN; k <<= 1) {
        for (int j = k >> 1; j > 0; j >>= 1) {
            for (int i = tid; i < NN; i += 256) {
                int ixj = i ^ j;
                if (ixj > i) {
                    uint64_t a = key[i], bb = key[ixj];
                    bool up = ((i & k) == 0);
                    if (up ? (a < bb) : (a > bb)) { key[i] = bb; key[ixj] = a; }
                }
            }
            __syncthreads();
        }
    }

    // ---- gather boxes in sorted order; scale + clip; area ----
    for (int i = tid; i < NN; i += 256) {
        uint64_t kk = key[i];
        int n = NN - 1 - (int)(kk & 0xffffffffULL);
        sidx[i] = n;
        float4 bp = *reinterpret_cast<const float4*>(boxes + ((size_t)((b * NN + n) * NC + c)) * 4);
        float x1 = fminf(fmaxf(bp.x * sx, 0.f), IMGW);
        float y1 = fminf(fmaxf(bp.y * sy, 0.f), IMGH);
        float x2 = fminf(fmaxf(bp.z * sx, 0.f), IMGW);
        float y2 = fminf(fmaxf(bp.w * sy, 0.f), IMGH);
        pbox[i] = make_float4(x1, y1, x2, y2);
        bar[i] = fmaxf(x2 - x1, 0.f) * fmaxf(y2 - y1, 0.f);
    }
    __syncthreads();

    // ---- suppression mask build: register-cached columns, zero LDS in inner loop
    // lane owns column j = w*64 + lane for w = 0..7 (40 VGPRs, loaded ONCE)
    float rx1[8], ry1[8], rx2[8], ry2[8], ra[8];
#pragma unroll
    for (int w = 0; w < 8; ++w) {
        float4 bb = pbox[(w << 6) | lane];
        rx1[w] = bb.x; ry1[w] = bb.y; rx2[w] = bb.z; ry2[w] = bb.w;
        ra[w] = bar[(w << 6) | lane];
    }
    // scalar wave id -> scalar row index -> uniform branches, static rb[] indexing
    const int wvu = __builtin_amdgcn_readfirstlane(tid >> 6);
    for (int k = 0; k < NN / 4; ++k) {
        const int i = wvu + 4 * k;          // scalar
        const float4 bi = pbox[i];          // broadcast read (uniform addr)
        const float ai = bar[i];
        const int w0 = i >> 6;
        // scalar mask of "j > i" within word w0 (double shift avoids UB at 64)
        const uint64_t jgt = (~0ull << (i & 63)) << 1;
#pragma unroll
        for (int w = 0; w < 8; ++w) {
            if (w > w0) {
                float dx = fminf(bi.z, rx2[w]) - fmaxf(bi.x, rx1[w]);
                float dy = fminf(bi.w, ry2[w]) - fmaxf(bi.y, ry1[w]);
                float inter = fmaxf(dx, 0.f) * fmaxf(dy, 0.f);
                float uni = ai + ra[w] - inter;
                uint64_t m = __ballot(inter > NMS_TH * fmaxf(uni, 1e-9f));
                if (lane == 0) maskT[w * MPITCH + i] = m;
            } else if (w == w0) {
                float dx = fminf(bi.z, rx2[w]) - fmaxf(bi.x, rx1[w]);
                float dy = fminf(bi.w, ry2[w]) - fmaxf(bi.y, ry1[w]);
                float inter = fmaxf(dx, 0.f) * fmaxf(dy, 0.f);
                float uni = ai + ra[w] - inter;
                uint64_t m = __ballot(inter > NMS_TH * fmaxf(uni, 1e-9f)) & jgt;
                if (lane == 0) maskT[w * MPITCH + i] = m;
            } else {
                if (lane == 0) maskT[w * MPITCH + i] = 0;
            }
        }
    }
    __syncthreads();

    // ---- serial scan (wave 0): 64 groups of 8 rows, prefetched one group ahead
    if (tid < 64) {
        uint64_t rem = 0;                 // lane (lane&7) accumulates removed word (lane&7)
        uint64_t mbB[8], mdB[8];
        const int myw = lane & 7;
#pragma unroll
        for (int t = 0; t < 8; ++t) {
            mbB[t] = maskT[0 * MPITCH + t];
            mdB[t] = maskT[myw * MPITCH + t];
        }
        uint64_t rw = 0, kw = 0;
        for (int i8 = 0; i8 < 64; ++i8) {
            uint64_t mbC[8], mdC[8];
#pragma unroll
            for (int t = 0; t < 8; ++t) { mbC[t] = mbB[t]; mdC[t] = mdB[t]; }
            const int nbase = i8 * 8 + 8;
            if (nbase < NN) {
                const int nw = nbase >> 6;
#pragma unroll
                for (int t = 0; t < 8; ++t) {
                    mbB[t] = maskT[nw * MPITCH + nbase + t];
                    mdB[t] = maskT[myw * MPITCH + nbase + t];
                }
            }
            const int bitbase = (i8 & 7) * 8;
#pragma unroll
            for (int t = 0; t < 8; ++t) {
                const int bit = bitbase + t;
                if (!((rw >> bit) & 1)) {
                    rw |= mbC[t];
                    rem |= mdC[t];
                    kw |= (1ull << bit);
                }
            }
            if ((i8 & 7) == 7) {
                const int w = i8 >> 3;
                if (lane == 0) keepw[w] = kw;
                kw = 0;
                const int wn = w + 1;
                if (wn < 8) {
                    uint32_t lo = __shfl((unsigned int)(rem & 0xffffffffULL), wn);
                    uint32_t hi = __shfl((unsigned int)(rem >> 32), wn);
                    rw = ((uint64_t)hi << 32) | lo;
                }
            }
        }
    }
    __syncthreads();

    // ---- output: kept boxes raise max_conf at their original index ----
    for (int r = tid; r < NN; r += 256) {
        if ((keepw[r >> 6] >> (r & 63)) & 1) {
            int bits = (int)(uint32_t)(key[r] >> 32);
            atomicMax((int*)maxconf + (b * NN + sidx[r]), bits);
        }
    }
}

// ---------------- Kernel 3: keep = (max_conf >= 0.5) ----------------
__global__ __launch_bounds__(256) void k_keep(float* __restrict__ out) {
    int i = blockIdx.x * 256 + threadIdx.x;
    if (i < NB * NN) out[NB * NN + i] = (out[i] >= SCORE_TH) ? 1.0f : 0.0f;
}

extern "C" void kernel_launch(void* const* d_in, const int* in_sizes, int n_in,
                              void* d_out, int out_size, void* d_ws, size_t ws_size,
                              hipStream_t stream) {
    const float* boxes  = (const float*)d_in[0];   // (8,512,80,4)
    const float* logits = (const float*)d_in[1];   // (8,512,81)
    const float* scale  = (const float*)d_in[2];   // (8,2)
    float* out = (float*)d_out;                    // [max_conf(4096) | keep(4096)]
    float* stats = (float*)d_ws;

    hipLaunchKernelGGL(k_softmax_stats, dim3(NB * NN), dim3(64), 0, stream, logits, stats, out);
    hipLaunchKernelGGL(k_nms, dim3(NB * NC), dim3(256), 0, stream,
                       boxes, logits, scale, stats, out);
    hipLaunchKernelGGL(k_keep, dim3((NB * NN + 255) / 256), dim3(256), 0, stream, out);
}